// Round 7
// baseline (591.618 us; speedup 1.0000x reference)
//
#include <hip/hip_runtime.h>
#include <hip/hip_bf16.h>

using bf16 = __hip_bfloat16;
typedef __attribute__((ext_vector_type(8))) short short8;   // 8 bf16 (4 VGPR)
typedef __attribute__((ext_vector_type(4))) short short4v;  // 4 bf16 (8 B)
typedef __attribute__((ext_vector_type(4))) float f32x4;

constexpr int BATCH = 32;
constexpr int INC = 3;
constexpr int OC = 64;
constexpr int HH = 64;
constexpr int WW = 64;
constexpr int KK = 5;
constexpr int HP = 32;
constexpr int WP = 32;
constexpr int NL = 16;
constexpr int LW = 128;
constexpr int OW = 100;

__device__ __forceinline__ float b2f(bf16 v) { return __bfloat162float(v); }
__device__ __forceinline__ short f2bs(float v) {
  bf16 h = __float2bfloat16(v);
  return *(short*)&h;
}

// ---------------- routing scores: conv(x, node_filter) -> global max ----------------
__global__ __launch_bounds__(256) void k_scores(
    const float* __restrict__ x, const float* __restrict__ nw,
    float* __restrict__ scores) {
  int d = blockIdx.x & 3;
  int b = blockIdx.x >> 2;
  int f = (2 << d) - 2;  // node filter index used at depth d: 0,2,6,14
  __shared__ float wsm[75];
  __shared__ float red[256];
  int t = threadIdx.x;
  if (t < 75) wsm[t] = nw[f * 75 + t];
  __syncthreads();
  float m = -3.0e38f;
  for (int p = t; p < HH * WW; p += 256) {
    int y = p >> 6, xx = p & 63;
    float s = 0.f;
    for (int ic = 0; ic < INC; ic++) {
      for (int ky = 0; ky < KK; ky++) {
        int yy = y + ky - 2;
        if (yy < 0 || yy >= HH) continue;
        const float* xr = x + ((b * INC + ic) * HH + yy) * WW;
        const float* wr = &wsm[(ic * KK + ky) * KK];
        for (int kx = 0; kx < KK; kx++) {
          int xc = xx + kx - 2;
          if (xc < 0 || xc >= WW) continue;
          s = fmaf(xr[xc], wr[kx], s);
        }
      }
    }
    m = fmaxf(m, s);
  }
  red[t] = m;
  __syncthreads();
  for (int s2 = 128; s2 > 0; s2 >>= 1) {
    if (t < s2) red[t] = fmaxf(red[t], red[t + s2]);
    __syncthreads();
  }
  if (t == 0) scores[d * BATCH + b] = red[0];
}

// ---------------- soft-routing mixture over the binary tree ----------------
__global__ void k_mix(const float* __restrict__ scores,
                      const float* __restrict__ nb, float* __restrict__ mix) {
  int t = threadIdx.x;
  int b = t >> 4, l = t & 15;
  float m = 1.f;
#pragma unroll
  for (int d = 0; d < 4; d++) {
    int j = l >> (3 - d);
    int i = j >> 1;
    int bit = j & 1;
    float z = scores[d * BATCH + b] + nb[(1 << d) - 1 + i];
    float be = 1.f / (1.f + expf(-z));
    m *= bit ? be : (1.f - be);
  }
  mix[b * NL + l] = m;
}

// ---------------- merged weight prep ----------------
__global__ __launch_bounds__(256) void k_prep(
    const float* __restrict__ cw1, const float* __restrict__ cw2,
    short* __restrict__ wA, short* __restrict__ wT) {
  int idx = blockIdx.x * 256 + threadIdx.x;
  if (idx < 98304) {
    int k = idx % 96;
    int rem = idx / 96;  // l*64 + oc
    float v = (k < 75) ? cw1[(size_t)rem * 75 + k] : 0.f;
    wA[(size_t)rem * 96 + k] = f2bs(v);
  } else {
    int i2 = idx - 98304;  // < 204800
    int icq = i2 & 7;
    int oc = (i2 >> 3) & 63;
    int rem = i2 >> 9;  // l*25 + tap
    short8 v;
#pragma unroll
    for (int j = 0; j < 8; j++) {
      int ic = icq * 8 + j;
      int l = rem / 25, tap = rem % 25;
      v[j] = f2bs(cw2[((size_t)(l * OC + oc) * OC + ic) * 25 + tap]);
    }
    *(short8*)(wT + ((size_t)rem * OC + oc) * OC + icq * 8) = v;
  }
}

// ---------------- conv1 via im2col + MFMA + in-register maxpool/relu -> h1t ----------------
__device__ __forceinline__ int slotbase(int col) {
  return col * 104 + 8 * ((-(col >> 1)) & 7);
}

__global__ __launch_bounds__(256) void k_conv1m(
    const float* __restrict__ x, const short* __restrict__ wA,
    short* __restrict__ h1t) {
  constexpr int BSZ = 64 * 104 + 64;
  constexpr int OTS = 72;
  __shared__ alignas(16) short Bm[2 * BSZ];
  __shared__ alignas(16) short ot[32 * OTS];
  int bid = blockIdx.x;
  int py = bid & 31;
  int b = bid >> 5;
  int t = threadIdx.x;
  int w = t >> 6, lane = t & 63;
  int n = lane & 15, q = lane >> 4;

  for (int i = t; i < BSZ; i += 256) ((int*)Bm)[i] = 0;
  __syncthreads();
  for (int i = t; i < 1200; i += 256) {
    int cg = i & 7;
    int kk = (i >> 3) % 75;
    int dy = (i >> 3) / 75;
    int ic = kk / 25, r25 = kk % 25;
    int ky = r25 / 5, kx = r25 % 5;
    int y = 2 * py + dy + ky - 2;
    const float* xr = x + ((size_t)(b * INC + ic) * HH + y) * WW;
    short* dst = Bm + dy * BSZ;
#pragma unroll
    for (int c8 = 0; c8 < 8; c8++) {
      int c = cg * 8 + c8;
      int cx = c + kx - 2;
      float v = 0.f;
      if (y >= 0 && y < HH && cx >= 0 && cx < WW) v = xr[cx];
      dst[slotbase(c) + kk] = f2bs(v);
    }
  }
  __syncthreads();

  short8 Acur[3], Anx[3];
#pragma unroll
  for (int ks = 0; ks < 3; ks++)
    Anx[ks] = *(const short8*)(wA + ((size_t)(w * 16 + n) * 96) + ks * 32 + q * 8);

  for (int l = 0; l < NL; l++) {
#pragma unroll
    for (int ks = 0; ks < 3; ks++) Acur[ks] = Anx[ks];
    if (l < NL - 1) {
#pragma unroll
      for (int ks = 0; ks < 3; ks++)
        Anx[ks] = *(const short8*)(wA + ((size_t)((l + 1) * OC + w * 16 + n) * 96) +
                                   ks * 32 + q * 8);
    }
    f32x4 acc[2][2][2];  // [dy][dx][half]
#pragma unroll
    for (int dy = 0; dy < 2; dy++)
#pragma unroll
      for (int dx = 0; dx < 2; dx++)
#pragma unroll
        for (int h = 0; h < 2; h++) acc[dy][dx][h] = f32x4{0.f, 0.f, 0.f, 0.f};

#pragma unroll
    for (int dy = 0; dy < 2; dy++)
#pragma unroll
      for (int dx = 0; dx < 2; dx++)
#pragma unroll
        for (int h = 0; h < 2; h++) {
          int col = 2 * (h * 16 + n) + dx;
          const short* bp = Bm + dy * BSZ + slotbase(col);
#pragma unroll
          for (int ks = 0; ks < 3; ks++) {
            short8 Bf = *(const short8*)(bp + ks * 32 + q * 8);
            acc[dy][dx][h] = __builtin_amdgcn_mfma_f32_16x16x32_bf16(
                Acur[ks], Bf, acc[dy][dx][h], 0, 0, 0);
          }
        }

#pragma unroll
    for (int h = 0; h < 2; h++) {
      short4v sv;
#pragma unroll
      for (int r = 0; r < 4; r++) {
        float v = fmaxf(fmaxf(acc[0][0][h][r], acc[0][1][h][r]),
                        fmaxf(acc[1][0][h][r], acc[1][1][h][r]));
        sv[r] = f2bs(fmaxf(v, 0.f));
      }
      *(short4v*)(&ot[(h * 16 + n) * OTS + w * 16 + q * 4]) = sv;
    }
    __syncthreads();
    {
      int px = t >> 3, seg = t & 7;
      short8 v = *(const short8*)(&ot[px * OTS + seg * 8]);
      *(short8*)(h1t + ((size_t)(l * BATCH + b) * (HP * WP) + py * WP + px) * OC +
                 seg * 8) = v;
    }
    __syncthreads();
  }
}

// ---------------- conv2 via MFMA implicit GEMM (2 ic-chunks) + spatial max -> pfeat -------
// grid: NL*BATCH*8 blocks (l, b, 4-row stripe), 256 threads = 4 waves.
// Wave w = output row (y0+w), 64 oc x 32 px; acc = 8 f32x4 (32 regs) for residency.
// LDS slab per chunk: [8 rows][36 cols][32 ic + 4 pad] bf16 = 23 KB.
__global__ __launch_bounds__(256, 4) void k_conv2m(
    const short* __restrict__ h1t, const short* __restrict__ wT,
    float* __restrict__ pfeat) {
  constexpr int CS = 40;        // 80 B: 16B-aligned; 2-way banks (free)
  constexpr int RS = 36 * CS;
  __shared__ alignas(16) short hs[8 * RS];  // 23,040 B
  __shared__ alignas(16) float sred[4][64];
  int bid = blockIdx.x;
  int stripe = bid & 7;
  int b = (bid >> 3) & 31;
  int l = bid >> 8;
  int t = threadIdx.x;
  int w = t >> 6, lane = t & 63;
  int n = lane & 15, q = lane >> 4;
  int y0 = stripe * 4;
  const short* hg = h1t + (size_t)(l * BATCH + b) * (HP * WP) * OC;
  const short* wbase = wT + (size_t)l * 25 * OC * OC;

  f32x4 acc[4][2];  // [octile][px half]
#pragma unroll
  for (int i = 0; i < 4; i++)
#pragma unroll
    for (int j = 0; j < 2; j++) acc[i][j] = f32x4{0.f, 0.f, 0.f, 0.f};

  short8 Acur[4], Anext[4];
  // A-frag: A[m=lane&15][k=q*8+j]; k = ic within current 32-chunk
#pragma unroll
  for (int oct = 0; oct < 4; oct++)
    Anext[oct] = *(const short8*)(wbase + (size_t)(oct * 16 + n) * OC + q * 8);

  for (int chunk = 0; chunk < 2; chunk++) {
    __syncthreads();  // protect hs from previous chunk's readers
    // stage with predication (halo written as zeros): 8r x 36c x 4 icq = 1152 short8
    for (int idx = t; idx < 8 * 36 * 4; idx += 256) {
      int icq = idx & 3;
      int c = (idx >> 2) % 36;
      int r = (idx >> 2) / 36;
      int y = y0 - 2 + r, xx = c - 2;
      short8 v = short8{0, 0, 0, 0, 0, 0, 0, 0};
      if (y >= 0 && y < HP && xx >= 0 && xx < WP)
        v = *(const short8*)(hg + (y * WP + xx) * OC + chunk * 32 + icq * 8);
      *(short8*)(&hs[r * RS + c * CS + icq * 8]) = v;
    }
    __syncthreads();
    for (int tap = 0; tap < 25; tap++) {
#pragma unroll
      for (int i = 0; i < 4; i++) Acur[i] = Anext[i];
      if (!(chunk == 1 && tap == 24)) {
        int ntap = tap + 1, nchunk = chunk;
        if (ntap == 25) { ntap = 0; nchunk = 1; }
        const short* tb = wbase + (size_t)ntap * OC * OC;
#pragma unroll
        for (int oct = 0; oct < 4; oct++)
          Anext[oct] = *(const short8*)(tb + (size_t)(oct * 16 + n) * OC +
                                        nchunk * 32 + q * 8);
      }
      int dy = tap / 5, dx = tap - 5 * dy;
      int lr = w + dy;  // local row in slab, 0..7
#pragma unroll
      for (int h = 0; h < 2; h++) {
        int c = h * 16 + n + dx;
        short8 B = *(const short8*)(&hs[lr * RS + c * CS + q * 8]);
#pragma unroll
        for (int oct = 0; oct < 4; oct++)
          acc[oct][h] = __builtin_amdgcn_mfma_f32_16x16x32_bf16(
              Acur[oct], B, acc[oct][h], 0, 0, 0);
      }
    }
  }

  // epilogue: max over this wave's 32 px; D layout: col(px)=lane&15, row(oc)=q*4+reg
#pragma unroll
  for (int oct = 0; oct < 4; oct++) {
    f32x4 m = acc[oct][0];
#pragma unroll
    for (int r = 0; r < 4; r++) m[r] = fmaxf(m[r], acc[oct][1][r]);
#pragma unroll
    for (int mask = 1; mask <= 8; mask <<= 1)
#pragma unroll
      for (int r = 0; r < 4; r++) m[r] = fmaxf(m[r], __shfl_xor(m[r], mask, 64));
    if (n == 0) *(f32x4*)&sred[w][oct * 16 + q * 4] = m;
  }
  __syncthreads();
  if (t < 64) {
    float m = fmaxf(fmaxf(sred[0][t], sred[1][t]), fmaxf(sred[2][t], sred[3][t]));
    pfeat[((size_t)(l * BATCH + b) * 8 + stripe) * OC + t] = m;
  }
}

// ---------------- per-leaf 2-layer MLP; folds stripe-max + relu ----------------
__global__ __launch_bounds__(128) void k_mlp(
    const float* __restrict__ pfeat, const float* __restrict__ w1s,
    const float* __restrict__ b1s, const float* __restrict__ w2s,
    const float* __restrict__ b2s, float* __restrict__ logits) {
  __shared__ float fs[OC];
  __shared__ float hid[LW];
  int bid = blockIdx.x;
  int b = bid & 31;
  int l = bid >> 5;
  int t = threadIdx.x;
  if (t < OC) {
    const float* pf = pfeat + (size_t)(l * BATCH + b) * 8 * OC;
    float m = pf[t];
#pragma unroll
    for (int s = 1; s < 8; s++) m = fmaxf(m, pf[s * OC + t]);
    fs[t] = fmaxf(m, 0.f);  // relu(global max)
  }
  __syncthreads();
  float h = b1s[l * LW + t];
  for (int c = 0; c < OC; c++)
    h = fmaf(fs[c], w1s[(l * OC + c) * LW + t], h);
  hid[t] = h;
  __syncthreads();
  if (t < OW) {
    float o = b2s[l * OW + t];
    for (int j = 0; j < LW; j++)
      o = fmaf(hid[j], w2s[(l * LW + j) * OW + t], o);
    logits[(size_t)(l * BATCH + b) * OW + t] = o;
  }
}

// ---------------- out[b,o] = sum_l mix[b,l] * logits[l,b,o]  (fp32 out) ----------------
__global__ __launch_bounds__(256) void k_combine(
    const float* __restrict__ logits, const float* __restrict__ mix,
    float* __restrict__ out) {
  int idx = blockIdx.x * 256 + threadIdx.x;
  if (idx >= BATCH * OW) return;
  int b = idx / OW, o = idx - b * OW;
  float s = 0.f;
#pragma unroll
  for (int l = 0; l < NL; l++)
    s = fmaf(mix[b * NL + l], logits[((size_t)l * BATCH + b) * OW + o], s);
  out[idx] = s;
}

extern "C" void kernel_launch(void* const* d_in, const int* in_sizes, int n_in,
                              void* d_out, int out_size, void* d_ws, size_t ws_size,
                              hipStream_t stream) {
  const float* x   = (const float*)d_in[0];
  const float* nw  = (const float*)d_in[1];
  const float* nb  = (const float*)d_in[2];
  const float* cw1 = (const float*)d_in[3];
  const float* cw2 = (const float*)d_in[4];
  const float* w1s = (const float*)d_in[5];
  const float* b1s = (const float*)d_in[6];
  const float* w2s = (const float*)d_in[7];
  const float* b2s = (const float*)d_in[8];
  float* out = (float*)d_out;

  char* ws = (char*)d_ws;
  short* h1t = (short*)ws;  // [l,b][px 1024][ic 64] bf16 = 67.1 MB
  size_t off = (size_t)NL * BATCH * HP * WP * OC * sizeof(short);
  short* wT = (short*)(ws + off); off += (size_t)NL * 25 * OC * OC * sizeof(short);
  short* wA = (short*)(ws + off); off += (size_t)NL * OC * 96 * sizeof(short);
  float* scores = (float*)(ws + off); off += 4 * BATCH * sizeof(float);
  float* mixp   = (float*)(ws + off); off += BATCH * NL * sizeof(float);
  float* pfeat  = (float*)(ws + off); off += (size_t)NL * BATCH * 8 * OC * sizeof(float);
  float* logits = (float*)(ws + off); off += (size_t)NL * BATCH * OW * sizeof(float);
  (void)ws_size; (void)in_sizes; (void)n_in; (void)out_size;

  k_scores<<<4 * BATCH, 256, 0, stream>>>(x, nw, scores);
  k_mix<<<1, BATCH * NL, 0, stream>>>(scores, nb, mixp);
  k_prep<<<(98304 + 204800) / 256, 256, 0, stream>>>(cw1, cw2, wA, wT);
  k_conv1m<<<BATCH * 32, 256, 0, stream>>>(x, wA, h1t);
  k_conv2m<<<NL * BATCH * 8, 256, 0, stream>>>(h1t, wT, pfeat);
  k_mlp<<<NL * BATCH, 128, 0, stream>>>(pfeat, w1s, b1s, w2s, b2s, logits);
  k_combine<<<(BATCH * OW + 255) / 256, 256, 0, stream>>>(logits, mixp, out);
}

// Round 8
// 348.558 us; speedup vs baseline: 1.6973x; 1.6973x over previous
//
#include <hip/hip_runtime.h>
#include <hip/hip_bf16.h>

using bf16 = __hip_bfloat16;
typedef __attribute__((ext_vector_type(8))) short short8;   // 8 bf16 (4 VGPR)
typedef __attribute__((ext_vector_type(4))) short short4v;  // 4 bf16 (8 B)
typedef __attribute__((ext_vector_type(4))) float f32x4;

constexpr int BATCH = 32;
constexpr int INC = 3;
constexpr int OC = 64;
constexpr int HH = 64;
constexpr int WW = 64;
constexpr int KK = 5;
constexpr int HP = 32;
constexpr int WP = 32;
constexpr int NL = 16;
constexpr int LW = 128;
constexpr int OW = 100;

__device__ __forceinline__ float b2f(bf16 v) { return __bfloat162float(v); }
__device__ __forceinline__ short f2bs(float v) {
  bf16 h = __float2bfloat16(v);
  return *(short*)&h;
}

// ---------------- routing scores: conv(x, node_filter) -> global max ----------------
__global__ __launch_bounds__(256) void k_scores(
    const float* __restrict__ x, const float* __restrict__ nw,
    float* __restrict__ scores) {
  int d = blockIdx.x & 3;
  int b = blockIdx.x >> 2;
  int f = (2 << d) - 2;  // node filter index used at depth d: 0,2,6,14
  __shared__ float wsm[75];
  __shared__ float red[256];
  int t = threadIdx.x;
  if (t < 75) wsm[t] = nw[f * 75 + t];
  __syncthreads();
  float m = -3.0e38f;
  for (int p = t; p < HH * WW; p += 256) {
    int y = p >> 6, xx = p & 63;
    float s = 0.f;
    for (int ic = 0; ic < INC; ic++) {
      for (int ky = 0; ky < KK; ky++) {
        int yy = y + ky - 2;
        if (yy < 0 || yy >= HH) continue;
        const float* xr = x + ((b * INC + ic) * HH + yy) * WW;
        const float* wr = &wsm[(ic * KK + ky) * KK];
        for (int kx = 0; kx < KK; kx++) {
          int xc = xx + kx - 2;
          if (xc < 0 || xc >= WW) continue;
          s = fmaf(xr[xc], wr[kx], s);
        }
      }
    }
    m = fmaxf(m, s);
  }
  red[t] = m;
  __syncthreads();
  for (int s2 = 128; s2 > 0; s2 >>= 1) {
    if (t < s2) red[t] = fmaxf(red[t], red[t + s2]);
    __syncthreads();
  }
  if (t == 0) scores[d * BATCH + b] = red[0];
}

// ---------------- soft-routing mixture over the binary tree ----------------
__global__ void k_mix(const float* __restrict__ scores,
                      const float* __restrict__ nb, float* __restrict__ mix) {
  int t = threadIdx.x;
  int b = t >> 4, l = t & 15;
  float m = 1.f;
#pragma unroll
  for (int d = 0; d < 4; d++) {
    int j = l >> (3 - d);
    int i = j >> 1;
    int bit = j & 1;
    float z = scores[d * BATCH + b] + nb[(1 << d) - 1 + i];
    float be = 1.f / (1.f + expf(-z));
    m *= bit ? be : (1.f - be);
  }
  mix[b * NL + l] = m;
}

// ---------------- merged weight prep ----------------
__global__ __launch_bounds__(256) void k_prep(
    const float* __restrict__ cw1, const float* __restrict__ cw2,
    short* __restrict__ wA, short* __restrict__ wT) {
  int idx = blockIdx.x * 256 + threadIdx.x;
  if (idx < 98304) {
    int k = idx % 96;
    int rem = idx / 96;  // l*64 + oc
    float v = (k < 75) ? cw1[(size_t)rem * 75 + k] : 0.f;
    wA[(size_t)rem * 96 + k] = f2bs(v);
  } else {
    int i2 = idx - 98304;  // < 204800
    int icq = i2 & 7;
    int oc = (i2 >> 3) & 63;
    int rem = i2 >> 9;  // l*25 + tap
    short8 v;
#pragma unroll
    for (int j = 0; j < 8; j++) {
      int ic = icq * 8 + j;
      int l = rem / 25, tap = rem % 25;
      v[j] = f2bs(cw2[((size_t)(l * OC + oc) * OC + ic) * 25 + tap]);
    }
    *(short8*)(wT + ((size_t)rem * OC + oc) * OC + icq * 8) = v;
  }
}

// ---------------- conv1 via im2col + MFMA + in-register maxpool/relu -> h1t ----------------
__device__ __forceinline__ int slotbase(int col) {
  return col * 104 + 8 * ((-(col >> 1)) & 7);
}

__global__ __launch_bounds__(256) void k_conv1m(
    const float* __restrict__ x, const short* __restrict__ wA,
    short* __restrict__ h1t) {
  constexpr int BSZ = 64 * 104 + 64;
  constexpr int OTS = 72;
  __shared__ alignas(16) short Bm[2 * BSZ];
  __shared__ alignas(16) short ot[32 * OTS];
  int bid = blockIdx.x;
  int py = bid & 31;
  int b = bid >> 5;
  int t = threadIdx.x;
  int w = t >> 6, lane = t & 63;
  int n = lane & 15, q = lane >> 4;

  for (int i = t; i < BSZ; i += 256) ((int*)Bm)[i] = 0;
  __syncthreads();
  for (int i = t; i < 1200; i += 256) {
    int cg = i & 7;
    int kk = (i >> 3) % 75;
    int dy = (i >> 3) / 75;
    int ic = kk / 25, r25 = kk % 25;
    int ky = r25 / 5, kx = r25 % 5;
    int y = 2 * py + dy + ky - 2;
    const float* xr = x + ((size_t)(b * INC + ic) * HH + y) * WW;
    short* dst = Bm + dy * BSZ;
#pragma unroll
    for (int c8 = 0; c8 < 8; c8++) {
      int c = cg * 8 + c8;
      int cx = c + kx - 2;
      float v = 0.f;
      if (y >= 0 && y < HH && cx >= 0 && cx < WW) v = xr[cx];
      dst[slotbase(c) + kk] = f2bs(v);
    }
  }
  __syncthreads();

  short8 Acur[3], Anx[3];
#pragma unroll
  for (int ks = 0; ks < 3; ks++)
    Anx[ks] = *(const short8*)(wA + ((size_t)(w * 16 + n) * 96) + ks * 32 + q * 8);

  for (int l = 0; l < NL; l++) {
#pragma unroll
    for (int ks = 0; ks < 3; ks++) Acur[ks] = Anx[ks];
    if (l < NL - 1) {
#pragma unroll
      for (int ks = 0; ks < 3; ks++)
        Anx[ks] = *(const short8*)(wA + ((size_t)((l + 1) * OC + w * 16 + n) * 96) +
                                   ks * 32 + q * 8);
    }
    f32x4 acc[2][2][2];  // [dy][dx][half]
#pragma unroll
    for (int dy = 0; dy < 2; dy++)
#pragma unroll
      for (int dx = 0; dx < 2; dx++)
#pragma unroll
        for (int h = 0; h < 2; h++) acc[dy][dx][h] = f32x4{0.f, 0.f, 0.f, 0.f};

#pragma unroll
    for (int dy = 0; dy < 2; dy++)
#pragma unroll
      for (int dx = 0; dx < 2; dx++)
#pragma unroll
        for (int h = 0; h < 2; h++) {
          int col = 2 * (h * 16 + n) + dx;
          const short* bp = Bm + dy * BSZ + slotbase(col);
#pragma unroll
          for (int ks = 0; ks < 3; ks++) {
            short8 Bf = *(const short8*)(bp + ks * 32 + q * 8);
            acc[dy][dx][h] = __builtin_amdgcn_mfma_f32_16x16x32_bf16(
                Acur[ks], Bf, acc[dy][dx][h], 0, 0, 0);
          }
        }

#pragma unroll
    for (int h = 0; h < 2; h++) {
      short4v sv;
#pragma unroll
      for (int r = 0; r < 4; r++) {
        float v = fmaxf(fmaxf(acc[0][0][h][r], acc[0][1][h][r]),
                        fmaxf(acc[1][0][h][r], acc[1][1][h][r]));
        sv[r] = f2bs(fmaxf(v, 0.f));
      }
      *(short4v*)(&ot[(h * 16 + n) * OTS + w * 16 + q * 4]) = sv;
    }
    __syncthreads();
    {
      int px = t >> 3, seg = t & 7;
      short8 v = *(const short8*)(&ot[px * OTS + seg * 8]);
      *(short8*)(h1t + ((size_t)(l * BATCH + b) * (HP * WP) + py * WP + px) * OC +
                 seg * 8) = v;
    }
    __syncthreads();
  }
}

// ---------------- conv2 via MFMA implicit GEMM + spatial max -> pfeat ----------------
// grid: NL*BATCH*2 blocks (l, b, 16-row half), 256 threads = 4 waves.
// Wave w = rows {4w..4w+3}: 64 oc x 128 px = 4 oct x 8 pxt (acc 128 VGPR).
// Per tap per wave: 4 A global loads + 8 ds_read_b128 feed 32 MFMA -> MFMA-bound.
// LDS slab per chunk: [20 rows][36 cols][32 ic + 4 pad] bf16 = 57.6 KB, 2 blocks/CU.
__global__ __launch_bounds__(256, 2) void k_conv2m(
    const short* __restrict__ h1t, const short* __restrict__ wT,
    float* __restrict__ pfeat) {
  constexpr int CS = 40;        // 80 B: 16B-aligned; 2-way banks (free)
  constexpr int RS = 36 * CS;
  __shared__ alignas(16) short hs[20 * RS];  // 57,600 B
  __shared__ alignas(16) float sred[4][64];
  int bid = blockIdx.x;
  int half = bid & 1;
  int b = (bid >> 1) & 31;
  int l = bid >> 6;
  int t = threadIdx.x;
  int w = t >> 6, lane = t & 63;
  int n = lane & 15, q = lane >> 4;
  int y0 = half * 16;
  const short* hg = h1t + (size_t)(l * BATCH + b) * (HP * WP) * OC;
  const short* wbase = wT + (size_t)l * 25 * OC * OC;

  f32x4 acc[4][8];  // [octile][pxtile: row(4) x colhalf(2)]
#pragma unroll
  for (int i = 0; i < 4; i++)
#pragma unroll
    for (int j = 0; j < 8; j++) acc[i][j] = f32x4{0.f, 0.f, 0.f, 0.f};

  short8 Acur[4], Anext[4];
  // A-frag: A[m=lane&15][k=q*8+j]; k = ic within current 32-chunk
#pragma unroll
  for (int oct = 0; oct < 4; oct++)
    Anext[oct] = *(const short8*)(wbase + (size_t)(oct * 16 + n) * OC + q * 8);

  for (int chunk = 0; chunk < 2; chunk++) {
    __syncthreads();  // protect hs from previous chunk's readers
    // stage with predication (halo written as zeros): 20r x 36c x 4 icq = 2880 short8
    for (int idx = t; idx < 20 * 36 * 4; idx += 256) {
      int icq = idx & 3;
      int c = (idx >> 2) % 36;
      int r = (idx >> 2) / 36;
      int y = y0 - 2 + r, xx = c - 2;
      short8 v = short8{0, 0, 0, 0, 0, 0, 0, 0};
      if (y >= 0 && y < HP && xx >= 0 && xx < WP)
        v = *(const short8*)(hg + (y * WP + xx) * OC + chunk * 32 + icq * 8);
      *(short8*)(&hs[r * RS + c * CS + icq * 8]) = v;
    }
    __syncthreads();
    for (int tap = 0; tap < 25; tap++) {
#pragma unroll
      for (int i = 0; i < 4; i++) Acur[i] = Anext[i];
      if (!(chunk == 1 && tap == 24)) {
        int ntap = tap + 1, nchunk = chunk;
        if (ntap == 25) { ntap = 0; nchunk = 1; }
        const short* tb = wbase + (size_t)ntap * OC * OC;
#pragma unroll
        for (int oct = 0; oct < 4; oct++)
          Anext[oct] = *(const short8*)(tb + (size_t)(oct * 16 + n) * OC +
                                        nchunk * 32 + q * 8);
      }
      int dy = tap / 5, dx = tap - 5 * dy;
#pragma unroll
      for (int pxt = 0; pxt < 8; pxt++) {
        int lr = 4 * w + (pxt >> 1) + dy;     // slab row
        int c = (pxt & 1) * 16 + n + dx;      // slab col
        short8 B = *(const short8*)(&hs[lr * RS + c * CS + q * 8]);
#pragma unroll
        for (int oct = 0; oct < 4; oct++)
          acc[oct][pxt] = __builtin_amdgcn_mfma_f32_16x16x32_bf16(
              Acur[oct], B, acc[oct][pxt], 0, 0, 0);
      }
    }
  }

  // epilogue: max over this wave's 128 px; D layout: col(px)=lane&15, row(oc)=q*4+reg
#pragma unroll
  for (int oct = 0; oct < 4; oct++) {
    f32x4 m = acc[oct][0];
#pragma unroll
    for (int pxt = 1; pxt < 8; pxt++)
#pragma unroll
      for (int r = 0; r < 4; r++) m[r] = fmaxf(m[r], acc[oct][pxt][r]);
#pragma unroll
    for (int mask = 1; mask <= 8; mask <<= 1)
#pragma unroll
      for (int r = 0; r < 4; r++) m[r] = fmaxf(m[r], __shfl_xor(m[r], mask, 64));
    if (n == 0) *(f32x4*)&sred[w][oct * 16 + q * 4] = m;
  }
  __syncthreads();
  if (t < 64) {
    float m = fmaxf(fmaxf(sred[0][t], sred[1][t]), fmaxf(sred[2][t], sred[3][t]));
    pfeat[((size_t)(l * BATCH + b) * 2 + half) * OC + t] = m;
  }
}

// ---------------- per-leaf 2-layer MLP; folds half-max + relu ----------------
__global__ __launch_bounds__(128) void k_mlp(
    const float* __restrict__ pfeat, const float* __restrict__ w1s,
    const float* __restrict__ b1s, const float* __restrict__ w2s,
    const float* __restrict__ b2s, float* __restrict__ logits) {
  __shared__ float fs[OC];
  __shared__ float hid[LW];
  int bid = blockIdx.x;
  int b = bid & 31;
  int l = bid >> 5;
  int t = threadIdx.x;
  if (t < OC) {
    const float* pf = pfeat + (size_t)(l * BATCH + b) * 2 * OC;
    fs[t] = fmaxf(fmaxf(pf[t], pf[OC + t]), 0.f);  // relu(global max)
  }
  __syncthreads();
  float h = b1s[l * LW + t];
  for (int c = 0; c < OC; c++)
    h = fmaf(fs[c], w1s[(l * OC + c) * LW + t], h);
  hid[t] = h;
  __syncthreads();
  if (t < OW) {
    float o = b2s[l * OW + t];
    for (int j = 0; j < LW; j++)
      o = fmaf(hid[j], w2s[(l * LW + j) * OW + t], o);
    logits[(size_t)(l * BATCH + b) * OW + t] = o;
  }
}

// ---------------- out[b,o] = sum_l mix[b,l] * logits[l,b,o]  (fp32 out) ----------------
__global__ __launch_bounds__(256) void k_combine(
    const float* __restrict__ logits, const float* __restrict__ mix,
    float* __restrict__ out) {
  int idx = blockIdx.x * 256 + threadIdx.x;
  if (idx >= BATCH * OW) return;
  int b = idx / OW, o = idx - b * OW;
  float s = 0.f;
#pragma unroll
  for (int l = 0; l < NL; l++)
    s = fmaf(mix[b * NL + l], logits[((size_t)l * BATCH + b) * OW + o], s);
  out[idx] = s;
}

extern "C" void kernel_launch(void* const* d_in, const int* in_sizes, int n_in,
                              void* d_out, int out_size, void* d_ws, size_t ws_size,
                              hipStream_t stream) {
  const float* x   = (const float*)d_in[0];
  const float* nw  = (const float*)d_in[1];
  const float* nb  = (const float*)d_in[2];
  const float* cw1 = (const float*)d_in[3];
  const float* cw2 = (const float*)d_in[4];
  const float* w1s = (const float*)d_in[5];
  const float* b1s = (const float*)d_in[6];
  const float* w2s = (const float*)d_in[7];
  const float* b2s = (const float*)d_in[8];
  float* out = (float*)d_out;

  char* ws = (char*)d_ws;
  short* h1t = (short*)ws;  // [l,b][px 1024][ic 64] bf16 = 67.1 MB
  size_t off = (size_t)NL * BATCH * HP * WP * OC * sizeof(short);
  short* wT = (short*)(ws + off); off += (size_t)NL * 25 * OC * OC * sizeof(short);
  short* wA = (short*)(ws + off); off += (size_t)NL * OC * 96 * sizeof(short);
  float* scores = (float*)(ws + off); off += 4 * BATCH * sizeof(float);
  float* mixp   = (float*)(ws + off); off += BATCH * NL * sizeof(float);
  float* pfeat  = (float*)(ws + off); off += (size_t)NL * BATCH * 2 * OC * sizeof(float);
  float* logits = (float*)(ws + off); off += (size_t)NL * BATCH * OW * sizeof(float);
  (void)ws_size; (void)in_sizes; (void)n_in; (void)out_size;

  k_scores<<<4 * BATCH, 256, 0, stream>>>(x, nw, scores);
  k_mix<<<1, BATCH * NL, 0, stream>>>(scores, nb, mixp);
  k_prep<<<(98304 + 204800) / 256, 256, 0, stream>>>(cw1, cw2, wA, wT);
  k_conv1m<<<BATCH * 32, 256, 0, stream>>>(x, wA, h1t);
  k_conv2m<<<NL * BATCH * 2, 256, 0, stream>>>(h1t, wT, pfeat);
  k_mlp<<<NL * BATCH, 128, 0, stream>>>(pfeat, w1s, b1s, w2s, b2s, logits);
  k_combine<<<(BATCH * OW + 255) / 256, 256, 0, stream>>>(logits, mixp, out);
}

// Round 12
// 347.807 us; speedup vs baseline: 1.7010x; 1.0022x over previous
//
#include <hip/hip_runtime.h>
#include <hip/hip_bf16.h>

using bf16 = __hip_bfloat16;
typedef __attribute__((ext_vector_type(8))) short short8;   // 8 bf16 (4 VGPR)
typedef __attribute__((ext_vector_type(4))) short short4v;  // 4 bf16 (8 B)
typedef __attribute__((ext_vector_type(4))) float f32x4;

constexpr int BATCH = 32;
constexpr int INC = 3;
constexpr int OC = 64;
constexpr int HH = 64;
constexpr int WW = 64;
constexpr int KK = 5;
constexpr int HP = 32;
constexpr int WP = 32;
constexpr int NL = 16;
constexpr int LW = 128;
constexpr int OW = 100;

__device__ __forceinline__ float b2f(bf16 v) { return __bfloat162float(v); }
__device__ __forceinline__ short f2bs(float v) {
  bf16 h = __float2bfloat16(v);
  return *(short*)&h;
}

// ---------------- routing scores: conv(x, node_filter) -> global max ----------------
__global__ __launch_bounds__(256) void k_scores(
    const float* __restrict__ x, const float* __restrict__ nw,
    float* __restrict__ scores) {
  int d = blockIdx.x & 3;
  int b = blockIdx.x >> 2;
  int f = (2 << d) - 2;  // node filter index used at depth d: 0,2,6,14
  __shared__ float wsm[75];
  __shared__ float red[256];
  int t = threadIdx.x;
  if (t < 75) wsm[t] = nw[f * 75 + t];
  __syncthreads();
  float m = -3.0e38f;
  for (int p = t; p < HH * WW; p += 256) {
    int y = p >> 6, xx = p & 63;
    float s = 0.f;
    for (int ic = 0; ic < INC; ic++) {
      for (int ky = 0; ky < KK; ky++) {
        int yy = y + ky - 2;
        if (yy < 0 || yy >= HH) continue;
        const float* xr = x + ((b * INC + ic) * HH + yy) * WW;
        const float* wr = &wsm[(ic * KK + ky) * KK];
        for (int kx = 0; kx < KK; kx++) {
          int xc = xx + kx - 2;
          if (xc < 0 || xc >= WW) continue;
          s = fmaf(xr[xc], wr[kx], s);
        }
      }
    }
    m = fmaxf(m, s);
  }
  red[t] = m;
  __syncthreads();
  for (int s2 = 128; s2 > 0; s2 >>= 1) {
    if (t < s2) red[t] = fmaxf(red[t], red[t + s2]);
    __syncthreads();
  }
  if (t == 0) scores[d * BATCH + b] = red[0];
}

// ---------------- soft-routing mixture over the binary tree ----------------
__global__ void k_mix(const float* __restrict__ scores,
                      const float* __restrict__ nb, float* __restrict__ mix) {
  int t = threadIdx.x;
  int b = t >> 4, l = t & 15;
  float m = 1.f;
#pragma unroll
  for (int d = 0; d < 4; d++) {
    int j = l >> (3 - d);
    int i = j >> 1;
    int bit = j & 1;
    float z = scores[d * BATCH + b] + nb[(1 << d) - 1 + i];
    float be = 1.f / (1.f + expf(-z));
    m *= bit ? be : (1.f - be);
  }
  mix[b * NL + l] = m;
}

// ---------------- merged weight prep ----------------
__global__ __launch_bounds__(256) void k_prep(
    const float* __restrict__ cw1, const float* __restrict__ cw2,
    short* __restrict__ wA, short* __restrict__ wT) {
  int idx = blockIdx.x * 256 + threadIdx.x;
  if (idx < 98304) {
    int k = idx % 96;
    int rem = idx / 96;  // l*64 + oc
    float v = (k < 75) ? cw1[(size_t)rem * 75 + k] : 0.f;
    wA[(size_t)rem * 96 + k] = f2bs(v);
  } else {
    int i2 = idx - 98304;  // < 204800
    int icq = i2 & 7;
    int oc = (i2 >> 3) & 63;
    int rem = i2 >> 9;  // l*25 + tap
    short8 v;
#pragma unroll
    for (int j = 0; j < 8; j++) {
      int ic = icq * 8 + j;
      int l = rem / 25, tap = rem % 25;
      v[j] = f2bs(cw2[((size_t)(l * OC + oc) * OC + ic) * 25 + tap]);
    }
    *(short8*)(wT + ((size_t)rem * OC + oc) * OC + icq * 8) = v;
  }
}

// ---------------- conv1 via im2col + MFMA + in-register maxpool/relu -> h1t ----------------
__device__ __forceinline__ int slotbase(int col) {
  return col * 104 + 8 * ((-(col >> 1)) & 7);
}

__global__ __launch_bounds__(256) void k_conv1m(
    const float* __restrict__ x, const short* __restrict__ wA,
    short* __restrict__ h1t) {
  constexpr int BSZ = 64 * 104 + 64;
  constexpr int OTS = 72;
  __shared__ alignas(16) short Bm[2 * BSZ];
  __shared__ alignas(16) short ot[32 * OTS];
  int bid = blockIdx.x;
  int py = bid & 31;
  int b = bid >> 5;
  int t = threadIdx.x;
  int w = t >> 6, lane = t & 63;
  int n = lane & 15, q = lane >> 4;

  for (int i = t; i < BSZ; i += 256) ((int*)Bm)[i] = 0;
  __syncthreads();
  for (int i = t; i < 1200; i += 256) {
    int cg = i & 7;
    int kk = (i >> 3) % 75;
    int dy = (i >> 3) / 75;
    int ic = kk / 25, r25 = kk % 25;
    int ky = r25 / 5, kx = r25 % 5;
    int y = 2 * py + dy + ky - 2;
    const float* xr = x + ((size_t)(b * INC + ic) * HH + y) * WW;
    short* dst = Bm + dy * BSZ;
#pragma unroll
    for (int c8 = 0; c8 < 8; c8++) {
      int c = cg * 8 + c8;
      int cx = c + kx - 2;
      float v = 0.f;
      if (y >= 0 && y < HH && cx >= 0 && cx < WW) v = xr[cx];
      dst[slotbase(c) + kk] = f2bs(v);
    }
  }
  __syncthreads();

  short8 Acur[3], Anx[3];
#pragma unroll
  for (int ks = 0; ks < 3; ks++)
    Anx[ks] = *(const short8*)(wA + ((size_t)(w * 16 + n) * 96) + ks * 32 + q * 8);

  for (int l = 0; l < NL; l++) {
#pragma unroll
    for (int ks = 0; ks < 3; ks++) Acur[ks] = Anx[ks];
    if (l < NL - 1) {
#pragma unroll
      for (int ks = 0; ks < 3; ks++)
        Anx[ks] = *(const short8*)(wA + ((size_t)((l + 1) * OC + w * 16 + n) * 96) +
                                   ks * 32 + q * 8);
    }
    f32x4 acc[2][2][2];  // [dy][dx][half]
#pragma unroll
    for (int dy = 0; dy < 2; dy++)
#pragma unroll
      for (int dx = 0; dx < 2; dx++)
#pragma unroll
        for (int h = 0; h < 2; h++) acc[dy][dx][h] = f32x4{0.f, 0.f, 0.f, 0.f};

#pragma unroll
    for (int dy = 0; dy < 2; dy++)
#pragma unroll
      for (int dx = 0; dx < 2; dx++)
#pragma unroll
        for (int h = 0; h < 2; h++) {
          int col = 2 * (h * 16 + n) + dx;
          const short* bp = Bm + dy * BSZ + slotbase(col);
#pragma unroll
          for (int ks = 0; ks < 3; ks++) {
            short8 Bf = *(const short8*)(bp + ks * 32 + q * 8);
            acc[dy][dx][h] = __builtin_amdgcn_mfma_f32_16x16x32_bf16(
                Acur[ks], Bf, acc[dy][dx][h], 0, 0, 0);
          }
        }

#pragma unroll
    for (int h = 0; h < 2; h++) {
      short4v sv;
#pragma unroll
      for (int r = 0; r < 4; r++) {
        float v = fmaxf(fmaxf(acc[0][0][h][r], acc[0][1][h][r]),
                        fmaxf(acc[1][0][h][r], acc[1][1][h][r]));
        sv[r] = f2bs(fmaxf(v, 0.f));
      }
      *(short4v*)(&ot[(h * 16 + n) * OTS + w * 16 + q * 4]) = sv;
    }
    __syncthreads();
    {
      int px = t >> 3, seg = t & 7;
      short8 v = *(const short8*)(&ot[px * OTS + seg * 8]);
      *(short8*)(h1t + ((size_t)(l * BATCH + b) * (HP * WP) + py * WP + px) * OC +
                 seg * 8) = v;
    }
    __syncthreads();
  }
}

// ---------------- conv2 via MFMA implicit GEMM + spatial max -> pfeat ----------------
// grid: NL*BATCH*2 blocks (l, b, 16-row half), 256 threads = 4 waves.
// Wave w = rows {4w..4w+3}: 64 oc x 128 px = 4 oct x 8 pxt (acc 128 VGPR).
// Per tap per wave: 4 A global loads + 8 ds_read_b128 feed 32 MFMA -> MFMA-bound.
// LDS slab per chunk: [20 rows][36 cols][32 ic + 4 pad] bf16 = 57.6 KB, 2 blocks/CU.
__global__ __launch_bounds__(256, 2) void k_conv2m(
    const short* __restrict__ h1t, const short* __restrict__ wT,
    float* __restrict__ pfeat) {
  constexpr int CS = 40;        // 80 B: 16B-aligned; 2-way banks (free)
  constexpr int RS = 36 * CS;
  __shared__ alignas(16) short hs[20 * RS];  // 57,600 B
  __shared__ alignas(16) float sred[4][64];
  int bid = blockIdx.x;
  int half = bid & 1;
  int b = (bid >> 1) & 31;
  int l = bid >> 6;
  int t = threadIdx.x;
  int w = t >> 6, lane = t & 63;
  int n = lane & 15, q = lane >> 4;
  int y0 = half * 16;
  const short* hg = h1t + (size_t)(l * BATCH + b) * (HP * WP) * OC;
  const short* wbase = wT + (size_t)l * 25 * OC * OC;

  f32x4 acc[4][8];  // [octile][pxtile: row(4) x colhalf(2)]
#pragma unroll
  for (int i = 0; i < 4; i++)
#pragma unroll
    for (int j = 0; j < 8; j++) acc[i][j] = f32x4{0.f, 0.f, 0.f, 0.f};

  short8 Acur[4], Anext[4];
  // A-frag: A[m=lane&15][k=q*8+j]; k = ic within current 32-chunk
#pragma unroll
  for (int oct = 0; oct < 4; oct++)
    Anext[oct] = *(const short8*)(wbase + (size_t)(oct * 16 + n) * OC + q * 8);

  for (int chunk = 0; chunk < 2; chunk++) {
    __syncthreads();  // protect hs from previous chunk's readers
    // stage with predication (halo written as zeros): 20r x 36c x 4 icq = 2880 short8
    for (int idx = t; idx < 20 * 36 * 4; idx += 256) {
      int icq = idx & 3;
      int c = (idx >> 2) % 36;
      int r = (idx >> 2) / 36;
      int y = y0 - 2 + r, xx = c - 2;
      short8 v = short8{0, 0, 0, 0, 0, 0, 0, 0};
      if (y >= 0 && y < HP && xx >= 0 && xx < WP)
        v = *(const short8*)(hg + (y * WP + xx) * OC + chunk * 32 + icq * 8);
      *(short8*)(&hs[r * RS + c * CS + icq * 8]) = v;
    }
    __syncthreads();
    for (int tap = 0; tap < 25; tap++) {
#pragma unroll
      for (int i = 0; i < 4; i++) Acur[i] = Anext[i];
      if (!(chunk == 1 && tap == 24)) {
        int ntap = tap + 1, nch = chunk;
        if (ntap == 25) { ntap = 0; nch = 1; }
        const short* tb = wbase + (size_t)ntap * OC * OC;
#pragma unroll
        for (int oct = 0; oct < 4; oct++)
          Anext[oct] = *(const short8*)(tb + (size_t)(oct * 16 + n) * OC +
                                        nch * 32 + q * 8);
      }
      int dy = tap / 5, dx = tap - 5 * dy;
#pragma unroll
      for (int pxt = 0; pxt < 8; pxt++) {
        int lr = 4 * w + (pxt >> 1) + dy;     // slab row
        int c = (pxt & 1) * 16 + n + dx;      // slab col
        short8 B = *(const short8*)(&hs[lr * RS + c * CS + q * 8]);
#pragma unroll
        for (int oct = 0; oct < 4; oct++)
          acc[oct][pxt] = __builtin_amdgcn_mfma_f32_16x16x32_bf16(
              Acur[oct], B, acc[oct][pxt], 0, 0, 0);
      }
    }
  }

  // epilogue: max over this wave's 128 px; D layout: col(px)=lane&15, row(oc)=q*4+reg
#pragma unroll
  for (int oct = 0; oct < 4; oct++) {
    f32x4 m = acc[oct][0];
#pragma unroll
    for (int pxt = 1; pxt < 8; pxt++)
#pragma unroll
      for (int r = 0; r < 4; r++) m[r] = fmaxf(m[r], acc[oct][pxt][r]);
#pragma unroll
    for (int mask = 1; mask <= 8; mask <<= 1)
#pragma unroll
      for (int r = 0; r < 4; r++) m[r] = fmaxf(m[r], __shfl_xor(m[r], mask, 64));
    if (n == 0) *(f32x4*)&sred[w][oct * 16 + q * 4] = m;
  }
  __syncthreads();
  if (t < 64) {
    float m = fmaxf(fmaxf(sred[0][t], sred[1][t]), fmaxf(sred[2][t], sred[3][t]));
    pfeat[((size_t)(l * BATCH + b) * 2 + half) * OC + t] = m;
  }
}

// ---------------- per-leaf 2-layer MLP; folds half-max + relu ----------------
__global__ __launch_bounds__(128) void k_mlp(
    const float* __restrict__ pfeat, const float* __restrict__ w1s,
    const float* __restrict__ b1s, const float* __restrict__ w2s,
    const float* __restrict__ b2s, float* __restrict__ logits) {
  __shared__ float fs[OC];
  __shared__ float hid[LW];
  int bid = blockIdx.x;
  int b = bid & 31;
  int l = bid >> 5;
  int t = threadIdx.x;
  if (t < OC) {
    const float* pf = pfeat + (size_t)(l * BATCH + b) * 2 * OC;
    fs[t] = fmaxf(fmaxf(pf[t], pf[OC + t]), 0.f);  // relu(global max)
  }
  __syncthreads();
  float h = b1s[l * LW + t];
  for (int c = 0; c < OC; c++)
    h = fmaf(fs[c], w1s[(l * OC + c) * LW + t], h);
  hid[t] = h;
  __syncthreads();
  if (t < OW) {
    float o = b2s[l * OW + t];
    for (int j = 0; j < LW; j++)
      o = fmaf(hid[j], w2s[(l * LW + j) * OW + t], o);
    logits[(size_t)(l * BATCH + b) * OW + t] = o;
  }
}

// ---------------- out[b,o] = sum_l mix[b,l] * logits[l,b,o]  (fp32 out) ----------------
__global__ __launch_bounds__(256) void k_combine(
    const float* __restrict__ logits, const float* __restrict__ mix,
    float* __restrict__ out) {
  int idx = blockIdx.x * 256 + threadIdx.x;
  if (idx >= BATCH * OW) return;
  int b = idx / OW, o = idx - b * OW;
  float s = 0.f;
#pragma unroll
  for (int l = 0; l < NL; l++)
    s = fmaf(mix[b * NL + l], logits[((size_t)l * BATCH + b) * OW + o], s);
  out[idx] = s;
}

extern "C" void kernel_launch(void* const* d_in, const int* in_sizes, int n_in,
                              void* d_out, int out_size, void* d_ws, size_t ws_size,
                              hipStream_t stream) {
  const float* x   = (const float*)d_in[0];
  const float* nw  = (const float*)d_in[1];
  const float* nb  = (const float*)d_in[2];
  const float* cw1 = (const float*)d_in[3];
  const float* cw2 = (const float*)d_in[4];
  const float* w1s = (const float*)d_in[5];
  const float* b1s = (const float*)d_in[6];
  const float* w2s = (const float*)d_in[7];
  const float* b2s = (const float*)d_in[8];
  float* out = (float*)d_out;

  char* ws = (char*)d_ws;
  short* h1t = (short*)ws;  // [l,b][px 1024][ic 64] bf16 = 67.1 MB
  size_t off = (size_t)NL * BATCH * HP * WP * OC * sizeof(short);
  short* wT = (short*)(ws + off); off += (size_t)NL * 25 * OC * OC * sizeof(short);
  short* wA = (short*)(ws + off); off += (size_t)NL * OC * 96 * sizeof(short);
  float* scores = (float*)(ws + off); off += 4 * BATCH * sizeof(float);
  float* mixp   = (float*)(ws + off); off += BATCH * NL * sizeof(float);
  float* pfeat  = (float*)(ws + off); off += (size_t)NL * BATCH * 2 * OC * sizeof(float);
  float* logits = (float*)(ws + off); off += (size_t)NL * BATCH * OW * sizeof(float);
  (void)ws_size; (void)in_sizes; (void)n_in; (void)out_size;

  k_scores<<<4 * BATCH, 256, 0, stream>>>(x, nw, scores);
  k_mix<<<1, BATCH * NL, 0, stream>>>(scores, nb, mixp);
  k_prep<<<(98304 + 204800) / 256, 256, 0, stream>>>(cw1, cw2, wA, wT);
  k_conv1m<<<BATCH * 32, 256, 0, stream>>>(x, wA, h1t);
  k_conv2m<<<NL * BATCH * 2, 256, 0, stream>>>(h1t, wT, pfeat);
  k_mlp<<<NL * BATCH, 128, 0, stream>>>(pfeat, w1s, b1s, w2s, b2s, logits);
  k_combine<<<(BATCH * OW + 255) / 256, 256, 0, stream>>>(logits, mixp, out);
}

// Round 14
// 281.800 us; speedup vs baseline: 2.0994x; 1.2342x over previous
//
#include <hip/hip_runtime.h>
#include <hip/hip_bf16.h>

using bf16 = __hip_bfloat16;
typedef __attribute__((ext_vector_type(8))) short short8;   // 8 bf16 (4 VGPR)
typedef __attribute__((ext_vector_type(4))) short short4v;  // 4 bf16 (8 B)
typedef __attribute__((ext_vector_type(4))) float f32x4;

constexpr int BATCH = 32;
constexpr int INC = 3;
constexpr int OC = 64;
constexpr int HH = 64;
constexpr int WW = 64;
constexpr int KK = 5;
constexpr int HP = 32;
constexpr int WP = 32;
constexpr int NL = 16;
constexpr int LW = 128;
constexpr int OW = 100;

__device__ __forceinline__ short f2bs(float v) {
  bf16 h = __float2bfloat16(v);
  return *(short*)&h;
}

// ---------------- routing scores (partial): conv(x, node_filter) -> 16-row-group max ------
// grid: 4 depths * 32 batch * 4 row-groups = 512 blocks, 256 threads
__global__ __launch_bounds__(256) void k_scores(
    const float* __restrict__ x, const float* __restrict__ nw,
    float* __restrict__ scores_p) {
  int bid = blockIdx.x;
  int d = bid & 3;
  int b = (bid >> 2) & 31;
  int g = bid >> 7;  // 0..3: rows 16g..16g+15
  int f = (2 << d) - 2;  // node filter index used at depth d: 0,2,6,14
  __shared__ float wsm[75];
  __shared__ float red[256];
  int t = threadIdx.x;
  if (t < 75) wsm[t] = nw[f * 75 + t];
  __syncthreads();
  float m = -3.0e38f;
  for (int p = g * 1024 + t; p < (g + 1) * 1024; p += 256) {
    int y = p >> 6, xx = p & 63;
    float s = 0.f;
    for (int ic = 0; ic < INC; ic++) {
      for (int ky = 0; ky < KK; ky++) {
        int yy = y + ky - 2;
        if (yy < 0 || yy >= HH) continue;
        const float* xr = x + ((b * INC + ic) * HH + yy) * WW;
        const float* wr = &wsm[(ic * KK + ky) * KK];
        for (int kx = 0; kx < KK; kx++) {
          int xc = xx + kx - 2;
          if (xc < 0 || xc >= WW) continue;
          s = fmaf(xr[xc], wr[kx], s);
        }
      }
    }
    m = fmaxf(m, s);
  }
  red[t] = m;
  __syncthreads();
  for (int s2 = 128; s2 > 0; s2 >>= 1) {
    if (t < s2) red[t] = fmaxf(red[t], red[t + s2]);
    __syncthreads();
  }
  if (t == 0) scores_p[(d * BATCH + b) * 4 + g] = red[0];
}

// ---------------- soft-routing mixture over the binary tree (folds 4 partial maxes) -------
__global__ void k_mix(const float* __restrict__ scores_p,
                      const float* __restrict__ nb, float* __restrict__ mix) {
  int t = threadIdx.x;
  int b = t >> 4, l = t & 15;
  float m = 1.f;
#pragma unroll
  for (int d = 0; d < 4; d++) {
    const float* sp = scores_p + (d * BATCH + b) * 4;
    float sc = fmaxf(fmaxf(sp[0], sp[1]), fmaxf(sp[2], sp[3]));
    int j = l >> (3 - d);
    int i = j >> 1;
    int bit = j & 1;
    float z = sc + nb[(1 << d) - 1 + i];
    float be = 1.f / (1.f + expf(-z));
    m *= bit ? be : (1.f - be);
  }
  mix[b * NL + l] = m;
}

// ---------------- merged weight prep ----------------
__global__ __launch_bounds__(256) void k_prep(
    const float* __restrict__ cw1, const float* __restrict__ cw2,
    short* __restrict__ wA, short* __restrict__ wT) {
  int idx = blockIdx.x * 256 + threadIdx.x;
  if (idx < 98304) {
    int k = idx % 96;
    int rem = idx / 96;  // l*64 + oc
    float v = (k < 75) ? cw1[(size_t)rem * 75 + k] : 0.f;
    wA[(size_t)rem * 96 + k] = f2bs(v);
  } else {
    int i2 = idx - 98304;  // < 204800
    int icq = i2 & 7;
    int oc = (i2 >> 3) & 63;
    int rem = i2 >> 9;  // l*25 + tap
    short8 v;
#pragma unroll
    for (int j = 0; j < 8; j++) {
      int ic = icq * 8 + j;
      int l = rem / 25, tap = rem % 25;
      v[j] = f2bs(cw2[((size_t)(l * OC + oc) * OC + ic) * 25 + tap]);
    }
    *(short8*)(wT + ((size_t)rem * OC + oc) * OC + icq * 8) = v;
  }
}

// ---------------- conv1 via im2col + MFMA + in-register maxpool/relu -> h1t ----------------
// (R8/R12 version verbatim — known-good on hardware)
__device__ __forceinline__ int slotbase(int col) {
  return col * 104 + 8 * ((-(col >> 1)) & 7);
}

__global__ __launch_bounds__(256) void k_conv1m(
    const float* __restrict__ x, const short* __restrict__ wA,
    short* __restrict__ h1t) {
  constexpr int BSZ = 64 * 104 + 64;
  constexpr int OTS = 72;
  __shared__ alignas(16) short Bm[2 * BSZ];
  __shared__ alignas(16) short ot[32 * OTS];
  int bid = blockIdx.x;
  int py = bid & 31;
  int b = bid >> 5;
  int t = threadIdx.x;
  int w = t >> 6, lane = t & 63;
  int n = lane & 15, q = lane >> 4;

  for (int i = t; i < BSZ; i += 256) ((int*)Bm)[i] = 0;
  __syncthreads();
  for (int i = t; i < 1200; i += 256) {
    int cg = i & 7;
    int kk = (i >> 3) % 75;
    int dy = (i >> 3) / 75;
    int ic = kk / 25, r25 = kk % 25;
    int ky = r25 / 5, kx = r25 % 5;
    int y = 2 * py + dy + ky - 2;
    const float* xr = x + ((size_t)(b * INC + ic) * HH + y) * WW;
    short* dst = Bm + dy * BSZ;
#pragma unroll
    for (int c8 = 0; c8 < 8; c8++) {
      int c = cg * 8 + c8;
      int cx = c + kx - 2;
      float v = 0.f;
      if (y >= 0 && y < HH && cx >= 0 && cx < WW) v = xr[cx];
      dst[slotbase(c) + kk] = f2bs(v);
    }
  }
  __syncthreads();

  short8 Acur[3], Anx[3];
#pragma unroll
  for (int ks = 0; ks < 3; ks++)
    Anx[ks] = *(const short8*)(wA + ((size_t)(w * 16 + n) * 96) + ks * 32 + q * 8);

  for (int l = 0; l < NL; l++) {
#pragma unroll
    for (int ks = 0; ks < 3; ks++) Acur[ks] = Anx[ks];
    if (l < NL - 1) {
#pragma unroll
      for (int ks = 0; ks < 3; ks++)
        Anx[ks] = *(const short8*)(wA + ((size_t)((l + 1) * OC + w * 16 + n) * 96) +
                                   ks * 32 + q * 8);
    }
    f32x4 acc[2][2][2];  // [dy][dx][half]
#pragma unroll
    for (int dy = 0; dy < 2; dy++)
#pragma unroll
      for (int dx = 0; dx < 2; dx++)
#pragma unroll
        for (int h = 0; h < 2; h++) acc[dy][dx][h] = f32x4{0.f, 0.f, 0.f, 0.f};

#pragma unroll
    for (int dy = 0; dy < 2; dy++)
#pragma unroll
      for (int dx = 0; dx < 2; dx++)
#pragma unroll
        for (int h = 0; h < 2; h++) {
          int col = 2 * (h * 16 + n) + dx;
          const short* bp = Bm + dy * BSZ + slotbase(col);
#pragma unroll
          for (int ks = 0; ks < 3; ks++) {
            short8 Bf = *(const short8*)(bp + ks * 32 + q * 8);
            acc[dy][dx][h] = __builtin_amdgcn_mfma_f32_16x16x32_bf16(
                Acur[ks], Bf, acc[dy][dx][h], 0, 0, 0);
          }
        }

#pragma unroll
    for (int h = 0; h < 2; h++) {
      short4v sv;
#pragma unroll
      for (int r = 0; r < 4; r++) {
        float v = fmaxf(fmaxf(acc[0][0][h][r], acc[0][1][h][r]),
                        fmaxf(acc[1][0][h][r], acc[1][1][h][r]));
        sv[r] = f2bs(fmaxf(v, 0.f));
      }
      *(short4v*)(&ot[(h * 16 + n) * OTS + w * 16 + q * 4]) = sv;
    }
    __syncthreads();
    {
      int px = t >> 3, seg = t & 7;
      short8 v = *(const short8*)(&ot[px * OTS + seg * 8]);
      *(short8*)(h1t + ((size_t)(l * BATCH + b) * (HP * WP) + py * WP + px) * OC +
                 seg * 8) = v;
    }
    __syncthreads();
  }
}

// ---------------- conv2 via MFMA implicit GEMM + spatial max -> pfeat ----------------
// (R8/R12 version verbatim — known-good on hardware; depth-1 A prefetch)
__global__ __launch_bounds__(256, 2) void k_conv2m(
    const short* __restrict__ h1t, const short* __restrict__ wT,
    float* __restrict__ pfeat) {
  constexpr int CS = 40;        // 80 B: 16B-aligned; 2-way banks (free)
  constexpr int RS = 36 * CS;
  __shared__ alignas(16) short hs[20 * RS];  // 57,600 B
  __shared__ alignas(16) float sred[4][64];
  int bid = blockIdx.x;
  int half = bid & 1;
  int b = (bid >> 1) & 31;
  int l = bid >> 6;
  int t = threadIdx.x;
  int w = t >> 6, lane = t & 63;
  int n = lane & 15, q = lane >> 4;
  int y0 = half * 16;
  const short* hg = h1t + (size_t)(l * BATCH + b) * (HP * WP) * OC;
  const short* wbase = wT + (size_t)l * 25 * OC * OC;

  f32x4 acc[4][8];  // [octile][pxtile: row(4) x colhalf(2)]
#pragma unroll
  for (int i = 0; i < 4; i++)
#pragma unroll
    for (int j = 0; j < 8; j++) acc[i][j] = f32x4{0.f, 0.f, 0.f, 0.f};

  short8 Acur[4], Anext[4];
  // A-frag: A[m=lane&15][k=q*8+j]; k = ic within current 32-chunk
#pragma unroll
  for (int oct = 0; oct < 4; oct++)
    Anext[oct] = *(const short8*)(wbase + (size_t)(oct * 16 + n) * OC + q * 8);

  for (int chunk = 0; chunk < 2; chunk++) {
    __syncthreads();  // protect hs from previous chunk's readers
    // stage with predication (halo written as zeros): 20r x 36c x 4 icq = 2880 short8
    for (int idx = t; idx < 20 * 36 * 4; idx += 256) {
      int icq = idx & 3;
      int c = (idx >> 2) % 36;
      int r = (idx >> 2) / 36;
      int y = y0 - 2 + r, xx = c - 2;
      short8 v = short8{0, 0, 0, 0, 0, 0, 0, 0};
      if (y >= 0 && y < HP && xx >= 0 && xx < WP)
        v = *(const short8*)(hg + (y * WP + xx) * OC + chunk * 32 + icq * 8);
      *(short8*)(&hs[r * RS + c * CS + icq * 8]) = v;
    }
    __syncthreads();
    for (int tap = 0; tap < 25; tap++) {
#pragma unroll
      for (int i = 0; i < 4; i++) Acur[i] = Anext[i];
      if (!(chunk == 1 && tap == 24)) {
        int ntap = tap + 1, nch = chunk;
        if (ntap == 25) { ntap = 0; nch = 1; }
        const short* tb = wbase + (size_t)ntap * OC * OC;
#pragma unroll
        for (int oct = 0; oct < 4; oct++)
          Anext[oct] = *(const short8*)(tb + (size_t)(oct * 16 + n) * OC +
                                        nch * 32 + q * 8);
      }
      int dy = tap / 5, dx = tap - 5 * dy;
#pragma unroll
      for (int pxt = 0; pxt < 8; pxt++) {
        int lr = 4 * w + (pxt >> 1) + dy;     // slab row
        int c = (pxt & 1) * 16 + n + dx;      // slab col
        short8 B = *(const short8*)(&hs[lr * RS + c * CS + q * 8]);
#pragma unroll
        for (int oct = 0; oct < 4; oct++)
          acc[oct][pxt] = __builtin_amdgcn_mfma_f32_16x16x32_bf16(
              Acur[oct], B, acc[oct][pxt], 0, 0, 0);
      }
    }
  }

  // epilogue: max over this wave's 128 px; D layout: col(px)=lane&15, row(oc)=q*4+reg
#pragma unroll
  for (int oct = 0; oct < 4; oct++) {
    f32x4 m = acc[oct][0];
#pragma unroll
    for (int pxt = 1; pxt < 8; pxt++)
#pragma unroll
      for (int r = 0; r < 4; r++) m[r] = fmaxf(m[r], acc[oct][pxt][r]);
#pragma unroll
    for (int mask = 1; mask <= 8; mask <<= 1)
#pragma unroll
      for (int r = 0; r < 4; r++) m[r] = fmaxf(m[r], __shfl_xor(m[r], mask, 64));
    if (n == 0) *(f32x4*)&sred[w][oct * 16 + q * 4] = m;
  }
  __syncthreads();
  if (t < 64) {
    float m = fmaxf(fmaxf(sred[0][t], sred[1][t]), fmaxf(sred[2][t], sred[3][t]));
    pfeat[((size_t)(l * BATCH + b) * 2 + half) * OC + t] = m;
  }
}

// ---------------- per-leaf 2-layer MLP; folds half-max + relu ----------------
__global__ __launch_bounds__(128) void k_mlp(
    const float* __restrict__ pfeat, const float* __restrict__ w1s,
    const float* __restrict__ b1s, const float* __restrict__ w2s,
    const float* __restrict__ b2s, float* __restrict__ logits) {
  __shared__ float fs[OC];
  __shared__ float hid[LW];
  int bid = blockIdx.x;
  int b = bid & 31;
  int l = bid >> 5;
  int t = threadIdx.x;
  if (t < OC) {
    const float* pf = pfeat + (size_t)(l * BATCH + b) * 2 * OC;
    fs[t] = fmaxf(fmaxf(pf[t], pf[OC + t]), 0.f);  // relu(global max)
  }
  __syncthreads();
  float h = b1s[l * LW + t];
  for (int c = 0; c < OC; c++)
    h = fmaf(fs[c], w1s[(l * OC + c) * LW + t], h);
  hid[t] = h;
  __syncthreads();
  if (t < OW) {
    float o = b2s[l * OW + t];
    for (int j = 0; j < LW; j++)
      o = fmaf(hid[j], w2s[(l * LW + j) * OW + t], o);
    logits[(size_t)(l * BATCH + b) * OW + t] = o;
  }
}

// ---------------- out[b,o] = sum_l mix[b,l] * logits[l,b,o]  (fp32 out) ----------------
__global__ __launch_bounds__(256) void k_combine(
    const float* __restrict__ logits, const float* __restrict__ mix,
    float* __restrict__ out) {
  int idx = blockIdx.x * 256 + threadIdx.x;
  if (idx >= BATCH * OW) return;
  int b = idx / OW, o = idx - b * OW;
  float s = 0.f;
#pragma unroll
  for (int l = 0; l < NL; l++)
    s = fmaf(mix[b * NL + l], logits[((size_t)l * BATCH + b) * OW + o], s);
  out[idx] = s;
}

extern "C" void kernel_launch(void* const* d_in, const int* in_sizes, int n_in,
                              void* d_out, int out_size, void* d_ws, size_t ws_size,
                              hipStream_t stream) {
  const float* x   = (const float*)d_in[0];
  const float* nw  = (const float*)d_in[1];
  const float* nb  = (const float*)d_in[2];
  const float* cw1 = (const float*)d_in[3];
  const float* cw2 = (const float*)d_in[4];
  const float* w1s = (const float*)d_in[5];
  const float* b1s = (const float*)d_in[6];
  const float* w2s = (const float*)d_in[7];
  const float* b2s = (const float*)d_in[8];
  float* out = (float*)d_out;

  char* ws = (char*)d_ws;
  short* h1t = (short*)ws;  // [l,b][px 1024][ic 64] bf16 = 67.1 MB
  size_t off = (size_t)NL * BATCH * HP * WP * OC * sizeof(short);
  short* wT = (short*)(ws + off); off += (size_t)NL * 25 * OC * OC * sizeof(short);
  short* wA = (short*)(ws + off); off += (size_t)NL * OC * 96 * sizeof(short);
  float* scores_p = (float*)(ws + off); off += 4 * BATCH * 4 * sizeof(float);
  float* mixp   = (float*)(ws + off); off += BATCH * NL * sizeof(float);
  float* pfeat  = (float*)(ws + off); off += (size_t)NL * BATCH * 2 * OC * sizeof(float);
  float* logits = (float*)(ws + off); off += (size_t)NL * BATCH * OW * sizeof(float);
  (void)ws_size; (void)in_sizes; (void)n_in; (void)out_size;

  k_scores<<<4 * BATCH * 4, 256, 0, stream>>>(x, nw, scores_p);
  k_mix<<<1, BATCH * NL, 0, stream>>>(scores_p, nb, mixp);
  k_prep<<<(98304 + 204800) / 256, 256, 0, stream>>>(cw1, cw2, wA, wT);
  k_conv1m<<<BATCH * 32, 256, 0, stream>>>(x, wA, h1t);
  k_conv2m<<<NL * BATCH * 2, 256, 0, stream>>>(h1t, wT, pfeat);
  k_mlp<<<NL * BATCH, 128, 0, stream>>>(pfeat, w1s, b1s, w2s, b2s, logits);
  k_combine<<<(BATCH * OW + 255) / 256, 256, 0, stream>>>(logits, mixp, out);
}